// Round 1
// baseline (5997.960 us; speedup 1.0000x reference)
//
#include <hip/hip_runtime.h>
#include <math.h>

#define TT 1024
#define NBATCH 8
#define BT 8192
#define NB 64

__device__ __forceinline__ float4 ld4(const float* p){ return *(const float4*)p; }

// ---------------- generic tiled fp32 GEMM, 64x64 tile, BK=16 ----------------
// C[bz] (MxN) = epi( sum_k A'[m][k] * B'[k][n] )
// A' = A (MxK, row stride lda) if !TA else A is stored K-major (A[(k)*lda + m])
// B' = B (KxN, row stride ldb) if !TB else B is NxK (B[(n)*ldb + k])
// grid = (N/64, M/64, batch)
template<int EPI, int TA, int TB>
__global__ __launch_bounds__(256)
void gemm_k(const float* __restrict__ A, const float* __restrict__ B,
            float* __restrict__ C, int K, int lda, int ldb, int ldc,
            long sA, long sB, long sC,
            const float* __restrict__ bias,
            const float* __restrict__ e1, long sE1,
            const float* __restrict__ e2, int k0p)
{
  const int bz = blockIdx.z;
  A += (long)bz * sA; B += (long)bz * sB; C += (long)bz * sC;
  if (e1) e1 += (long)bz * sE1;
  __shared__ float As[16][68];
  __shared__ float Bs[16][68];
  const int m0 = blockIdx.y * 64, n0 = blockIdx.x * 64;
  const int tid = threadIdx.x;
  const int tx = tid & 15, ty = tid >> 4;
  float acc[4][4] = {};
  for (int kk = 0; kk < K; kk += 16) {
    if (!TA) {
      int row = tid >> 2, kq = (tid & 3) << 2;
      float4 v = ld4(A + (long)(m0 + row) * lda + kk + kq);
      As[kq+0][row] = v.x; As[kq+1][row] = v.y; As[kq+2][row] = v.z; As[kq+3][row] = v.w;
    } else {
      int k = tid >> 4, mq = (tid & 15) << 2;
      *(float4*)&As[k][mq] = ld4(A + (long)(kk + k) * lda + m0 + mq);
    }
    if (!TB) {
      int k = tid >> 4, nq = (tid & 15) << 2;
      *(float4*)&Bs[k][nq] = ld4(B + (long)(kk + k) * ldb + n0 + nq);
    } else {
      int row = tid >> 2, kq = (tid & 3) << 2;
      float4 v = ld4(B + (long)(n0 + row) * ldb + kk + kq);
      Bs[kq+0][row] = v.x; Bs[kq+1][row] = v.y; Bs[kq+2][row] = v.z; Bs[kq+3][row] = v.w;
    }
    __syncthreads();
#pragma unroll
    for (int k = 0; k < 16; ++k) {
      float a[4], b[4];
      *(float4*)a = *(const float4*)&As[k][ty << 2];
      *(float4*)b = *(const float4*)&Bs[k][tx << 2];
#pragma unroll
      for (int i = 0; i < 4; ++i)
#pragma unroll
        for (int j = 0; j < 4; ++j) acc[i][j] = fmaf(a[i], b[j], acc[i][j]);
    }
    __syncthreads();
  }
#pragma unroll
  for (int i = 0; i < 4; ++i) {
    int m = m0 + (ty << 2) + i;
#pragma unroll
    for (int j = 0; j < 4; ++j) {
      int n = n0 + (tx << 2) + j;
      float v = acc[i][j];
      float* cp = C + (long)m * ldc + n;
      if (EPI == 0) *cp = v;
      else if (EPI == 1) *cp = tanhf(v + bias[n]);
      else if (EPI == 2) *cp = (m == n) ? 0.f : expf(tanhf(v));
      else if (EPI == 3) *cp = fmaxf(v + bias[n], 0.f);
      else if (EPI == 4) *cp = v + e1[m] * e2[n];
      else if (EPI == 5) {
        bool rowK = (m >= k0p && m < k0p + NB);
        bool colK = (n >= k0p && n < k0p + NB);
        float out;
        if (rowK) out = e1[(long)(m - k0p) * TT + n];
        else      out = (colK ? 0.f : *cp) - v;
        *cp = out;
      }
    }
  }
}

// ---------------- feature split ----------------
__global__ void split_k(const float* __restrict__ in, float* __restrict__ sem, float* __restrict__ str){
  long row = blockIdx.x;
  int c = threadIdx.x << 2;
  float4 v = ld4(in + row * 1024 + c);
  float* dst;
  if (c < 256)      dst = sem + row * 512 + c;
  else if (c < 512) dst = str + row * 512 + (c - 256);
  else if (c < 768) dst = sem + row * 512 + 256 + (c - 512);
  else              dst = str + row * 512 + 256 + (c - 768);
  *(float4*)dst = v;
}

// ---------------- f_i = exp(tanh(str . wfi)) ----------------
__global__ void fi_k(const float* __restrict__ str, const float* __restrict__ wfi, float* __restrict__ fi){
  int row = blockIdx.x * 4 + (threadIdx.x >> 6);
  int lane = threadIdx.x & 63;
  const float* p = str + (long)row * 512;
  float acc = 0.f;
  for (int c = lane; c < 512; c += 64) acc = fmaf(p[c], wfi[c], acc);
  for (int off = 32; off; off >>= 1) acc += __shfl_down(acc, off, 64);
  if (lane == 0) fi[row] = expf(tanhf(acc));
}

// ---------------- column sums of A ----------------
__global__ void colsum_k(const float* __restrict__ A, float* __restrict__ cs){
  int b = blockIdx.y;
  int j = blockIdx.x * 256 + threadIdx.x;
  const float* p = A + (long)b * TT * TT + j;
  float acc = 0.f;
  for (int i = 0; i < TT; ++i) acc += p[(long)i * TT];
  cs[b * TT + j] = acc;
}

// ---------------- build L_bar ----------------
__global__ void buildw_k(const float* __restrict__ A, const float* __restrict__ fi,
                         const float* __restrict__ cs, float* __restrict__ W){
  long idx = (long)blockIdx.x * 256 + threadIdx.x;
  long b = idx >> 20;
  long r = idx & 1048575;
  int i = (int)(r >> 10), j = (int)(r & 1023);
  float v;
  if (i == 0)      v = fi[b * TT + j];
  else if (i == j) v = cs[b * TT + j];
  else             v = -A[idx];
  W[idx] = v;
}

// ---------------- GJ: invert 64x64 diag block ----------------
__global__ __launch_bounds__(64) void gj_dinv_k(const float* __restrict__ W, float* __restrict__ Dinv, int k0){
  int b = blockIdx.x;
  __shared__ float P[64][129];
  const float* Wb = W + (long)b * TT * TT;
  int tid = threadIdx.x;
  for (int idx = tid; idx < 4096; idx += 64) {
    int r = idx >> 6, c = idx & 63;
    P[r][c] = Wb[(long)(k0 + r) * TT + k0 + c];
    P[r][64 + c] = (r == c) ? 1.f : 0.f;
  }
  __syncthreads();
  for (int k = 0; k < 64; ++k) {
    float pr = 1.f / P[k][k];
    __syncthreads();
    for (int c = tid; c < 128; c += 64) P[k][c] *= pr;
    __syncthreads();
    int r = tid;
    if (r != k) {
      float f = P[r][k];
      for (int c = 0; c < 128; ++c) P[r][c] -= f * P[k][c];
    }
    __syncthreads();
  }
  for (int idx = tid; idx < 4096; idx += 64) {
    int r = idx >> 6, c = idx & 63;
    Dinv[b * 4096 + idx] = P[r][64 + c];
  }
}

// ---------------- GJ: Rnew = Dinv @ W[K,:], cols K := Dinv ----------------
__global__ __launch_bounds__(256) void gj_rnew_k(const float* __restrict__ W, const float* __restrict__ Dinv,
                                                 float* __restrict__ Rnew, int k0){
  int b = blockIdx.y;
  const float* Wb = W + (long)b * TT * TT;
  const float* Db = Dinv + b * 4096;
  int idx = blockIdx.x * 256 + threadIdx.x;
  int p = idx >> 10, j = idx & 1023;
  float acc = 0.f;
  for (int q = 0; q < 64; ++q) acc = fmaf(Db[p * 64 + q], Wb[(long)(k0 + q) * TT + j], acc);
  if (j >= k0 && j < k0 + NB) acc = Db[p * 64 + (j - k0)];
  Rnew[(long)b * 65536 + idx] = acc;
}

// ---------------- GJ: save column panel ----------------
__global__ void gj_cold_k(const float* __restrict__ W, float* __restrict__ Cold, int k0){
  int b = blockIdx.y;
  int idx = blockIdx.x * 256 + threadIdx.x;
  int i = idx >> 6, q = idx & 63;
  Cold[(long)b * 65536 + idx] = W[(long)b * TT * TT + (long)i * TT + k0 + q];
}

// ---------------- d0, diag, df[:,0] ----------------
__global__ void ddiag_k(const float* __restrict__ W, const float* __restrict__ fi,
                        float* __restrict__ d0, float* __restrict__ diag, float* __restrict__ dfout){
  int t = blockIdx.x * 256 + threadIdx.x;
  int b = t >> 10, i = t & 1023;
  const float* Wb = W + (long)b * TT * TT;
  float dv = fi[t] * Wb[(long)i * TT];
  d0[t] = dv;
  diag[t] = Wb[(long)i * TT + i];
  dfout[(long)b * TT * 1025 + (long)i * 1025] = dv;
}

// ---------------- dx (in-place over A) + transposed df store ----------------
__global__ __launch_bounds__(256) void dx_k(float* __restrict__ A, const float* __restrict__ W,
                                            const float* __restrict__ diag, float* __restrict__ dfout){
  int b = blockIdx.z;
  int i0 = blockIdx.y * 64, j0 = blockIdx.x * 64;
  const float* Wb = W + (long)b * TT * TT;
  float* Ab = A + (long)b * TT * TT;
  __shared__ float Ls[64][65];
  __shared__ float Sx[64][65];
  int tid = threadIdx.x;
  for (int idx = tid; idx < 4096; idx += 256) {
    int r = idx >> 6, c = idx & 63;
    Ls[r][c] = Wb[(long)(j0 + r) * TT + i0 + c];   // LLinv[j][i] tile
  }
  __syncthreads();
  for (int idx = tid; idx < 4096; idx += 256) {
    int r = idx >> 6, c = idx & 63;
    int i = i0 + r, j = j0 + c;
    float a = Ab[(long)i * TT + j];
    float v = 0.f;
    if (j > 0) v = a * diag[b * TT + j];
    if (i > 0) v -= a * Ls[c][r];
    Ab[(long)i * TT + j] = v;
    Sx[r][c] = v;
  }
  __syncthreads();
  float* dfb = dfout + (long)b * TT * 1025;
  for (int idx = tid; idx < 4096; idx += 256) {
    int r = idx >> 6, c = idx & 63;
    dfb[(long)(j0 + r) * 1025 + i0 + 1 + c] = Sx[c][r];   // df[t=j][k=i+1] = dx[i][j]
  }
}

// ---------------- concat [sem | pinp | cinp] ----------------
__global__ void concat_k(const float* __restrict__ sem, const float* __restrict__ pinp,
                         const float* __restrict__ cinp, float* __restrict__ finp){
  long idx = ((long)blockIdx.x * 256 + threadIdx.x) << 2;
  long row = idx / 1536; int col = (int)(idx % 1536);
  float4 v;
  if (col < 512)       v = ld4(sem  + row * 512 + col);
  else if (col < 1024) v = ld4(pinp + row * 512 + (col - 512));
  else                 v = ld4(cinp + row * 512 + (col - 1024));
  *(float4*)(finp + idx) = v;
}

extern "C" void kernel_launch(void* const* d_in, const int* in_sizes, int n_in,
                              void* d_out, int out_size, void* d_ws, size_t ws_size,
                              hipStream_t stream){
  const float* input   = (const float*)d_in[0];
  const float* Wtp     = (const float*)d_in[1];
  const float* btp     = (const float*)d_in[2];
  const float* Wtc     = (const float*)d_in[3];
  const float* btc     = (const float*)d_in[4];
  const float* wfi     = (const float*)d_in[5];
  const float* Wbil    = (const float*)d_in[6];
  const float* exparam = (const float*)d_in[7];
  const float* Wfz     = (const float*)d_in[8];
  const float* bfz     = (const float*)d_in[9];

  if (ws_size < 156000000UL) return;   // need ~148.3 MB of scratch

  float* ws   = (float*)d_ws;
  float* sem  = ws;                 // 8192*512
  float* strv = ws + 4194304;       // 8192*512
  float* tp   = ws + 8388608;       // 8192*512
  float* tc   = ws + 12582912;      // 8192*512
  float* tpw  = ws + 16777216;      // 8192*512
  float* Abuf = ws + 20971520;      // 8*1024*1024  (later dx in-place, then finp reuse)
  float* Wbuf = ws + 29360128;      // 8*1024*1024  (becomes LLinv)
  float* fi   = ws + 37748736;      // 8192
  float* cs   = ws + 37756928;      // 8192
  float* d0   = ws + 37765120;      // 8192
  float* dg   = ws + 37773312;      // 8192
  float* Dinv = ws + 37781504;      // 8*64*64
  float* Cold = ws + 37814272;      // 8*1024*64
  float* Rnew = ws + 38338560;      // 8*64*1024
  float* finp = Abuf;               // 8192*1536, overlaps dead Abuf/Wbuf

  float* outp = (float*)d_out;          // 8192*512
  float* dfp  = outp + 4194304;         // 8192*1025

  split_k<<<8192, 256, 0, stream>>>(input, sem, strv);
  // tp = tanh(str @ Wtp^T + btp), tc likewise
  gemm_k<1,0,1><<<dim3(8,128,1),256,0,stream>>>(strv, Wtp, tp, 512, 512, 512, 512, 0,0,0, btp, nullptr,0,nullptr,0);
  gemm_k<1,0,1><<<dim3(8,128,1),256,0,stream>>>(strv, Wtc, tc, 512, 512, 512, 512, 0,0,0, btc, nullptr,0,nullptr,0);
  fi_k<<<2048,256,0,stream>>>(strv, wfi, fi);
  // tpw = tp @ Wbil
  gemm_k<0,0,0><<<dim3(8,128,1),256,0,stream>>>(tp, Wbil, tpw, 512, 512, 512, 512, 0,0,0, nullptr, nullptr,0,nullptr,0);
  // A = exp(tanh(tpw_b @ tc_b^T)) with zero diagonal
  gemm_k<2,0,1><<<dim3(16,16,8),256,0,stream>>>(tpw, tc, Abuf, 512, 512, 512, 1024, 524288, 524288, 1048576, nullptr, nullptr,0,nullptr,0);
  colsum_k<<<dim3(4,8),256,0,stream>>>(Abuf, cs);
  buildw_k<<<32768,256,0,stream>>>(Abuf, fi, cs, Wbuf);
  // blocked in-place Gauss-Jordan inverse (no pivoting), 16 block steps
  for (int k0 = 0; k0 < TT; k0 += NB) {
    gj_dinv_k<<<8,64,0,stream>>>(Wbuf, Dinv, k0);
    gj_cold_k<<<dim3(256,8),256,0,stream>>>(Wbuf, Cold, k0);
    gj_rnew_k<<<dim3(256,8),256,0,stream>>>(Wbuf, Dinv, Rnew, k0);
    gemm_k<5,0,0><<<dim3(16,16,8),256,0,stream>>>(Cold, Rnew, Wbuf, 64, 64, 1024, 1024, 65536, 65536, 1048576, nullptr, Rnew, 65536, nullptr, k0);
  }
  ddiag_k<<<32,256,0,stream>>>(Wbuf, fi, d0, dg, dfp);
  dx_k<<<dim3(16,16,8),256,0,stream>>>(Abuf, Wbuf, dg, dfp);
  // pinp = dx^T @ sem + d0 (x) exparam   -> strv buffer (dead)
  gemm_k<4,1,0><<<dim3(8,16,8),256,0,stream>>>(Abuf, sem, strv, 1024, 1024, 512, 512, 1048576, 524288, 524288, nullptr, d0, 1024, exparam, 0);
  // cinp = dx @ sem                       -> tp buffer (dead)
  gemm_k<0,0,0><<<dim3(8,16,8),256,0,stream>>>(Abuf, sem, tp, 1024, 1024, 512, 512, 1048576, 524288, 524288, nullptr, nullptr,0,nullptr,0);
  concat_k<<<12288,256,0,stream>>>(sem, strv, tp, finp);
  // out = relu(finp @ Wfz^T + bfz)
  gemm_k<3,0,1><<<dim3(8,128,1),256,0,stream>>>(finp, Wfz, outp, 1536, 1536, 1536, 512, 0,0,0, bfz, nullptr,0,nullptr,0);
}

// Round 2
// 5084.001 us; speedup vs baseline: 1.1798x; 1.1798x over previous
//
#include <hip/hip_runtime.h>
#include <math.h>

#define TT 1024
#define NBATCH 8
#define BT 8192
#define NB 64

__device__ __forceinline__ float4 ld4(const float* p){ return *(const float4*)p; }
__device__ __forceinline__ float rdlane(float v, int lane){
  return __int_as_float(__builtin_amdgcn_readlane(__float_as_int(v), lane));
}

// ---------------- generic tiled fp32 GEMM, 64x64 tile, BK=16 ----------------
template<int EPI, int TA, int TB>
__global__ __launch_bounds__(256)
void gemm_k(const float* __restrict__ A, const float* __restrict__ B,
            float* __restrict__ C, int K, int lda, int ldb, int ldc,
            long sA, long sB, long sC,
            const float* __restrict__ bias,
            const float* __restrict__ e1, long sE1,
            const float* __restrict__ e2, int k0p)
{
  const int bz = blockIdx.z;
  A += (long)bz * sA; B += (long)bz * sB; C += (long)bz * sC;
  if (e1) e1 += (long)bz * sE1;
  __shared__ float As[16][68];
  __shared__ float Bs[16][68];
  const int m0 = blockIdx.y * 64, n0 = blockIdx.x * 64;
  const int tid = threadIdx.x;
  const int tx = tid & 15, ty = tid >> 4;
  float acc[4][4] = {};
  for (int kk = 0; kk < K; kk += 16) {
    if (!TA) {
      int row = tid >> 2, kq = (tid & 3) << 2;
      float4 v = ld4(A + (long)(m0 + row) * lda + kk + kq);
      As[kq+0][row] = v.x; As[kq+1][row] = v.y; As[kq+2][row] = v.z; As[kq+3][row] = v.w;
    } else {
      int k = tid >> 4, mq = (tid & 15) << 2;
      *(float4*)&As[k][mq] = ld4(A + (long)(kk + k) * lda + m0 + mq);
    }
    if (!TB) {
      int k = tid >> 4, nq = (tid & 15) << 2;
      *(float4*)&Bs[k][nq] = ld4(B + (long)(kk + k) * ldb + n0 + nq);
    } else {
      int row = tid >> 2, kq = (tid & 3) << 2;
      float4 v = ld4(B + (long)(n0 + row) * ldb + kk + kq);
      Bs[kq+0][row] = v.x; Bs[kq+1][row] = v.y; Bs[kq+2][row] = v.z; Bs[kq+3][row] = v.w;
    }
    __syncthreads();
#pragma unroll
    for (int k = 0; k < 16; ++k) {
      float a[4], b[4];
      *(float4*)a = *(const float4*)&As[k][ty << 2];
      *(float4*)b = *(const float4*)&Bs[k][tx << 2];
#pragma unroll
      for (int i = 0; i < 4; ++i)
#pragma unroll
        for (int j = 0; j < 4; ++j) acc[i][j] = fmaf(a[i], b[j], acc[i][j]);
    }
    __syncthreads();
  }
#pragma unroll
  for (int i = 0; i < 4; ++i) {
    int m = m0 + (ty << 2) + i;
#pragma unroll
    for (int j = 0; j < 4; ++j) {
      int n = n0 + (tx << 2) + j;
      float v = acc[i][j];
      float* cp = C + (long)m * ldc + n;
      if (EPI == 0) *cp = v;
      else if (EPI == 1) *cp = tanhf(v + bias[n]);
      else if (EPI == 2) *cp = (m == n) ? 0.f : expf(tanhf(v));
      else if (EPI == 3) *cp = fmaxf(v + bias[n], 0.f);
      else if (EPI == 4) *cp = v + e1[m] * e2[n];
      else if (EPI == 5) {
        bool rowK = (m >= k0p && m < k0p + NB);
        bool colK = (n >= k0p && n < k0p + NB);
        float out;
        if (rowK) out = e1[(long)(m - k0p) * TT + n];
        else      out = (colK ? 0.f : *cp) - v;
        *cp = out;
      }
    }
  }
}

// ---------------- feature split ----------------
__global__ void split_k(const float* __restrict__ in, float* __restrict__ sem, float* __restrict__ str){
  long row = blockIdx.x;
  int c = threadIdx.x << 2;
  float4 v = ld4(in + row * 1024 + c);
  float* dst;
  if (c < 256)      dst = sem + row * 512 + c;
  else if (c < 512) dst = str + row * 512 + (c - 256);
  else if (c < 768) dst = sem + row * 512 + 256 + (c - 512);
  else              dst = str + row * 512 + 256 + (c - 768);
  *(float4*)dst = v;
}

// ---------------- f_i = exp(tanh(str . wfi)) ----------------
__global__ void fi_k(const float* __restrict__ str, const float* __restrict__ wfi, float* __restrict__ fi){
  int row = blockIdx.x * 4 + (threadIdx.x >> 6);
  int lane = threadIdx.x & 63;
  const float* p = str + (long)row * 512;
  float acc = 0.f;
  for (int c = lane; c < 512; c += 64) acc = fmaf(p[c], wfi[c], acc);
  for (int off = 32; off; off >>= 1) acc += __shfl_down(acc, off, 64);
  if (lane == 0) fi[row] = expf(tanhf(acc));
}

// ---------------- column sums of A ----------------
__global__ void colsum_k(const float* __restrict__ A, float* __restrict__ cs){
  int b = blockIdx.y;
  int j = blockIdx.x * 256 + threadIdx.x;
  const float* p = A + (long)b * TT * TT + j;
  float acc = 0.f;
  for (int i = 0; i < TT; ++i) acc += p[(long)i * TT];
  cs[b * TT + j] = acc;
}

// ---------------- build L_bar ----------------
__global__ void buildw_k(const float* __restrict__ A, const float* __restrict__ fi,
                         const float* __restrict__ cs, float* __restrict__ W){
  long idx = (long)blockIdx.x * 256 + threadIdx.x;
  long b = idx >> 20;
  long r = idx & 1048575;
  int i = (int)(r >> 10), j = (int)(r & 1023);
  float v;
  if (i == 0)      v = fi[b * TT + j];
  else if (i == j) v = cs[b * TT + j];
  else             v = -A[idx];
  W[idx] = v;
}

// ---------------- GJ: invert 64x64 diag block (register-resident, 1 wave/matrix) ----------------
// lane r holds row r of the 64x64 block entirely in VGPRs; compact in-place
// Gauss-Jordan without pivoting, fully unrolled so all reg indices are static.
__global__ __launch_bounds__(64) void gj_dinv_k(const float* __restrict__ W, float* __restrict__ Dinv, int k0){
  int b = blockIdx.x;
  int r = threadIdx.x;
  const float* Wb = W + (long)b * TT * TT + (long)(k0 + r) * TT + k0;
  float row[64];
#pragma unroll
  for (int c = 0; c < 64; c += 4) {
    float4 v = ld4(Wb + c);
    row[c] = v.x; row[c+1] = v.y; row[c+2] = v.z; row[c+3] = v.w;
  }
#pragma unroll
  for (int k = 0; k < 64; ++k) {
    float pk = rdlane(row[k], k);     // P[k][k]
    float pr = 1.f / pk;
    float f = row[k];                 // P[r][k]
    bool piv = (r == k);
#pragma unroll
    for (int c = 0; c < 64; ++c) {
      if (c == k) continue;
      float bc = rdlane(row[c], k);   // P[k][c]
      float sc = bc * pr;             // scaled pivot-row value
      float upd = fmaf(-f, sc, row[c]);
      row[c] = piv ? sc : upd;
    }
    row[k] = piv ? pr : -f * pr;
  }
  float* Db = Dinv + b * 4096 + r * 64;
#pragma unroll
  for (int c = 0; c < 64; c += 4) {
    float4 v; v.x = row[c]; v.y = row[c+1]; v.z = row[c+2]; v.w = row[c+3];
    *(float4*)(Db + c) = v;
  }
}

// ---------------- GJ: fused {Rnew = Dinv @ W[K,:] (cols K := Dinv)} + {Cold = W[:,K]} ----------------
__global__ __launch_bounds__(256) void gj_prep_k(const float* __restrict__ W, const float* __restrict__ Dinv,
                                                 float* __restrict__ Cold, float* __restrict__ Rnew, int k0){
  int b = blockIdx.y;
  int bx = blockIdx.x;
  if (bx < 256) {
    const float* Wb = W + (long)b * TT * TT;
    const float* Db = Dinv + b * 4096;
    int idx = bx * 256 + threadIdx.x;
    int p = idx >> 10, j = idx & 1023;
    float acc = 0.f;
    for (int q = 0; q < 64; ++q) acc = fmaf(Db[p * 64 + q], Wb[(long)(k0 + q) * TT + j], acc);
    if (j >= k0 && j < k0 + NB) acc = Db[p * 64 + (j - k0)];
    Rnew[(long)b * 65536 + idx] = acc;
  } else {
    int idx = (bx - 256) * 256 + threadIdx.x;
    int i = idx >> 6, q = idx & 63;
    Cold[(long)b * 65536 + idx] = W[(long)b * TT * TT + (long)i * TT + k0 + q];
  }
}

// ---------------- d0, diag, df[:,0] ----------------
__global__ void ddiag_k(const float* __restrict__ W, const float* __restrict__ fi,
                        float* __restrict__ d0, float* __restrict__ diag, float* __restrict__ dfout){
  int t = blockIdx.x * 256 + threadIdx.x;
  int b = t >> 10, i = t & 1023;
  const float* Wb = W + (long)b * TT * TT;
  float dv = fi[t] * Wb[(long)i * TT];
  d0[t] = dv;
  diag[t] = Wb[(long)i * TT + i];
  dfout[(long)b * TT * 1025 + (long)i * 1025] = dv;
}

// ---------------- dx (in-place over A) + transposed df store ----------------
__global__ __launch_bounds__(256) void dx_k(float* __restrict__ A, const float* __restrict__ W,
                                            const float* __restrict__ diag, float* __restrict__ dfout){
  int b = blockIdx.z;
  int i0 = blockIdx.y * 64, j0 = blockIdx.x * 64;
  const float* Wb = W + (long)b * TT * TT;
  float* Ab = A + (long)b * TT * TT;
  __shared__ float Ls[64][65];
  __shared__ float Sx[64][65];
  int tid = threadIdx.x;
  for (int idx = tid; idx < 4096; idx += 256) {
    int r = idx >> 6, c = idx & 63;
    Ls[r][c] = Wb[(long)(j0 + r) * TT + i0 + c];   // LLinv[j][i] tile
  }
  __syncthreads();
  for (int idx = tid; idx < 4096; idx += 256) {
    int r = idx >> 6, c = idx & 63;
    int i = i0 + r, j = j0 + c;
    float a = Ab[(long)i * TT + j];
    float v = 0.f;
    if (j > 0) v = a * diag[b * TT + j];
    if (i > 0) v -= a * Ls[c][r];
    Ab[(long)i * TT + j] = v;
    Sx[r][c] = v;
  }
  __syncthreads();
  float* dfb = dfout + (long)b * TT * 1025;
  for (int idx = tid; idx < 4096; idx += 256) {
    int r = idx >> 6, c = idx & 63;
    dfb[(long)(j0 + r) * 1025 + i0 + 1 + c] = Sx[c][r];   // df[t=j][k=i+1] = dx[i][j]
  }
}

// ---------------- concat [sem | pinp | cinp] ----------------
__global__ void concat_k(const float* __restrict__ sem, const float* __restrict__ pinp,
                         const float* __restrict__ cinp, float* __restrict__ finp){
  long idx = ((long)blockIdx.x * 256 + threadIdx.x) << 2;
  long row = idx / 1536; int col = (int)(idx % 1536);
  float4 v;
  if (col < 512)       v = ld4(sem  + row * 512 + col);
  else if (col < 1024) v = ld4(pinp + row * 512 + (col - 512));
  else                 v = ld4(cinp + row * 512 + (col - 1024));
  *(float4*)(finp + idx) = v;
}

extern "C" void kernel_launch(void* const* d_in, const int* in_sizes, int n_in,
                              void* d_out, int out_size, void* d_ws, size_t ws_size,
                              hipStream_t stream){
  const float* input   = (const float*)d_in[0];
  const float* Wtp     = (const float*)d_in[1];
  const float* btp     = (const float*)d_in[2];
  const float* Wtc     = (const float*)d_in[3];
  const float* btc     = (const float*)d_in[4];
  const float* wfi     = (const float*)d_in[5];
  const float* Wbil    = (const float*)d_in[6];
  const float* exparam = (const float*)d_in[7];
  const float* Wfz     = (const float*)d_in[8];
  const float* bfz     = (const float*)d_in[9];

  if (ws_size < 156000000UL) return;   // need ~148.3 MB of scratch

  float* ws   = (float*)d_ws;
  float* sem  = ws;                 // 8192*512
  float* strv = ws + 4194304;       // 8192*512
  float* tp   = ws + 8388608;       // 8192*512
  float* tc   = ws + 12582912;      // 8192*512
  float* tpw  = ws + 16777216;      // 8192*512
  float* Abuf = ws + 20971520;      // 8*1024*1024  (later dx in-place, then finp reuse)
  float* Wbuf = ws + 29360128;      // 8*1024*1024  (becomes LLinv)
  float* fi   = ws + 37748736;      // 8192
  float* cs   = ws + 37756928;      // 8192
  float* d0   = ws + 37765120;      // 8192
  float* dg   = ws + 37773312;      // 8192
  float* Dinv = ws + 37781504;      // 8*64*64
  float* Cold = ws + 37814272;      // 8*1024*64
  float* Rnew = ws + 38338560;      // 8*64*1024
  float* finp = Abuf;               // 8192*1536, overlaps dead Abuf/Wbuf

  float* outp = (float*)d_out;          // 8192*512
  float* dfp  = outp + 4194304;         // 8192*1025

  split_k<<<8192, 256, 0, stream>>>(input, sem, strv);
  gemm_k<1,0,1><<<dim3(8,128,1),256,0,stream>>>(strv, Wtp, tp, 512, 512, 512, 512, 0,0,0, btp, nullptr,0,nullptr,0);
  gemm_k<1,0,1><<<dim3(8,128,1),256,0,stream>>>(strv, Wtc, tc, 512, 512, 512, 512, 0,0,0, btc, nullptr,0,nullptr,0);
  fi_k<<<2048,256,0,stream>>>(strv, wfi, fi);
  gemm_k<0,0,0><<<dim3(8,128,1),256,0,stream>>>(tp, Wbil, tpw, 512, 512, 512, 512, 0,0,0, nullptr, nullptr,0,nullptr,0);
  gemm_k<2,0,1><<<dim3(16,16,8),256,0,stream>>>(tpw, tc, Abuf, 512, 512, 512, 1024, 524288, 524288, 1048576, nullptr, nullptr,0,nullptr,0);
  colsum_k<<<dim3(4,8),256,0,stream>>>(Abuf, cs);
  buildw_k<<<32768,256,0,stream>>>(Abuf, fi, cs, Wbuf);
  // blocked in-place Gauss-Jordan inverse (no pivoting), 16 block steps
  for (int k0 = 0; k0 < TT; k0 += NB) {
    gj_dinv_k<<<8,64,0,stream>>>(Wbuf, Dinv, k0);
    gj_prep_k<<<dim3(512,8),256,0,stream>>>(Wbuf, Dinv, Cold, Rnew, k0);
    gemm_k<5,0,0><<<dim3(16,16,8),256,0,stream>>>(Cold, Rnew, Wbuf, 64, 64, 1024, 1024, 65536, 65536, 1048576, nullptr, Rnew, 65536, nullptr, k0);
  }
  ddiag_k<<<32,256,0,stream>>>(Wbuf, fi, d0, dg, dfp);
  dx_k<<<dim3(16,16,8),256,0,stream>>>(Abuf, Wbuf, dg, dfp);
  gemm_k<4,1,0><<<dim3(8,16,8),256,0,stream>>>(Abuf, sem, strv, 1024, 1024, 512, 512, 1048576, 524288, 524288, nullptr, d0, 1024, exparam, 0);
  gemm_k<0,0,0><<<dim3(8,16,8),256,0,stream>>>(Abuf, sem, tp, 1024, 1024, 512, 512, 1048576, 524288, 524288, nullptr, nullptr,0,nullptr,0);
  concat_k<<<12288,256,0,stream>>>(sem, strv, tp, finp);
  gemm_k<3,0,1><<<dim3(8,128,1),256,0,stream>>>(finp, Wfz, outp, 1536, 1536, 1536, 512, 0,0,0, bfz, nullptr,0,nullptr,0);
}

// Round 3
// 2094.669 us; speedup vs baseline: 2.8634x; 2.4271x over previous
//
#include <hip/hip_runtime.h>
#include <math.h>

#define TT 1024
#define NBATCH 8
#define BT 8192
#define NB 64

__device__ __forceinline__ float4 ld4(const float* p){ return *(const float4*)p; }
__device__ __forceinline__ float rdlane(float v, int lane){
  return __int_as_float(__builtin_amdgcn_readlane(__float_as_int(v), lane));
}

// ---------------- generic tiled fp32 GEMM, 64x64 tile, BK=16 ----------------
template<int EPI, int TA, int TB>
__global__ __launch_bounds__(256)
void gemm_k(const float* __restrict__ A, const float* __restrict__ B,
            float* __restrict__ C, int K, int lda, int ldb, int ldc,
            long sA, long sB, long sC,
            const float* __restrict__ bias,
            const float* __restrict__ e1, long sE1,
            const float* __restrict__ e2, int k0p)
{
  const int bz = blockIdx.z;
  A += (long)bz * sA; B += (long)bz * sB; C += (long)bz * sC;
  if (e1) e1 += (long)bz * sE1;
  __shared__ float As[16][68];
  __shared__ float Bs[16][68];
  const int m0 = blockIdx.y * 64, n0 = blockIdx.x * 64;
  const int tid = threadIdx.x;
  const int tx = tid & 15, ty = tid >> 4;
  float acc[4][4] = {};
  for (int kk = 0; kk < K; kk += 16) {
    if (!TA) {
      int row = tid >> 2, kq = (tid & 3) << 2;
      float4 v = ld4(A + (long)(m0 + row) * lda + kk + kq);
      As[kq+0][row] = v.x; As[kq+1][row] = v.y; As[kq+2][row] = v.z; As[kq+3][row] = v.w;
    } else {
      int k = tid >> 4, mq = (tid & 15) << 2;
      *(float4*)&As[k][mq] = ld4(A + (long)(kk + k) * lda + m0 + mq);
    }
    if (!TB) {
      int k = tid >> 4, nq = (tid & 15) << 2;
      *(float4*)&Bs[k][nq] = ld4(B + (long)(kk + k) * ldb + n0 + nq);
    } else {
      int row = tid >> 2, kq = (tid & 3) << 2;
      float4 v = ld4(B + (long)(n0 + row) * ldb + kk + kq);
      Bs[kq+0][row] = v.x; Bs[kq+1][row] = v.y; Bs[kq+2][row] = v.z; Bs[kq+3][row] = v.w;
    }
    __syncthreads();
#pragma unroll
    for (int k = 0; k < 16; ++k) {
      float a[4], b[4];
      *(float4*)a = *(const float4*)&As[k][ty << 2];
      *(float4*)b = *(const float4*)&Bs[k][tx << 2];
#pragma unroll
      for (int i = 0; i < 4; ++i)
#pragma unroll
        for (int j = 0; j < 4; ++j) acc[i][j] = fmaf(a[i], b[j], acc[i][j]);
    }
    __syncthreads();
  }
#pragma unroll
  for (int i = 0; i < 4; ++i) {
    int m = m0 + (ty << 2) + i;
#pragma unroll
    for (int j = 0; j < 4; ++j) {
      int n = n0 + (tx << 2) + j;
      float v = acc[i][j];
      float* cp = C + (long)m * ldc + n;
      if (EPI == 0) *cp = v;
      else if (EPI == 1) *cp = tanhf(v + bias[n]);
      else if (EPI == 2) *cp = (m == n) ? 0.f : expf(tanhf(v));
      else if (EPI == 3) *cp = fmaxf(v + bias[n], 0.f);
      else if (EPI == 4) *cp = v + e1[m] * e2[n];
      else if (EPI == 5) {
        bool rowK = (m >= k0p && m < k0p + NB);
        bool colK = (n >= k0p && n < k0p + NB);
        float out;
        if (rowK) out = e1[(long)(m - k0p) * TT + n];
        else      out = (colK ? 0.f : *cp) - v;
        *cp = out;
      }
    }
  }
}

// ---------------- feature split ----------------
__global__ void split_k(const float* __restrict__ in, float* __restrict__ sem, float* __restrict__ str){
  long row = blockIdx.x;
  int c = threadIdx.x << 2;
  float4 v = ld4(in + row * 1024 + c);
  float* dst;
  if (c < 256)      dst = sem + row * 512 + c;
  else if (c < 512) dst = str + row * 512 + (c - 256);
  else if (c < 768) dst = sem + row * 512 + 256 + (c - 512);
  else              dst = str + row * 512 + 256 + (c - 768);
  *(float4*)dst = v;
}

// ---------------- f_i = exp(tanh(str . wfi)) ----------------
__global__ void fi_k(const float* __restrict__ str, const float* __restrict__ wfi, float* __restrict__ fi){
  int row = blockIdx.x * 4 + (threadIdx.x >> 6);
  int lane = threadIdx.x & 63;
  const float* p = str + (long)row * 512;
  float acc = 0.f;
  for (int c = lane; c < 512; c += 64) acc = fmaf(p[c], wfi[c], acc);
  for (int off = 32; off; off >>= 1) acc += __shfl_down(acc, off, 64);
  if (lane == 0) fi[row] = expf(tanhf(acc));
}

// ---------------- column sums of A ----------------
__global__ void colsum_k(const float* __restrict__ A, float* __restrict__ cs){
  int b = blockIdx.y;
  int j = blockIdx.x * 256 + threadIdx.x;
  const float* p = A + (long)b * TT * TT + j;
  float acc = 0.f;
  for (int i = 0; i < TT; ++i) acc += p[(long)i * TT];
  cs[b * TT + j] = acc;
}

// ---------------- build L_bar ----------------
__global__ void buildw_k(const float* __restrict__ A, const float* __restrict__ fi,
                         const float* __restrict__ cs, float* __restrict__ W){
  long idx = (long)blockIdx.x * 256 + threadIdx.x;
  long b = idx >> 20;
  long r = idx & 1048575;
  int i = (int)(r >> 10), j = (int)(r & 1023);
  float v;
  if (i == 0)      v = fi[b * TT + j];
  else if (i == j) v = cs[b * TT + j];
  else             v = -A[idx];
  W[idx] = v;
}

// ---------------- GJ: invert 64x64 diag block (register-resident, 1 wave/matrix) ----------------
// lane r holds row r of the 64x64 block in 64 VGPRs. Compact in-place
// Gauss-Jordan without pivoting. Macro-forced full unroll: EVERY register
// index is a literal constant (a #pragma unroll failed here -> scratch spill).
#define GJ_COL(c) { float bc = rdlane(row[(c)], (K_));            \
                    float z  = piv ? 0.f : row[(c)];              \
                    row[(c)] = fmaf(-t, bc, z); }
#define GJ_C4(c)  GJ_COL(c) GJ_COL((c)+1) GJ_COL((c)+2) GJ_COL((c)+3)
#define GJ_C16(c) GJ_C4(c) GJ_C4((c)+4) GJ_C4((c)+8) GJ_C4((c)+12)
#define GJ_C64    GJ_C16(0) GJ_C16(16) GJ_C16(32) GJ_C16(48)
#define GJ_STEP(k) { enum { K_ = (k) };                           \
                     float pk = rdlane(row[K_], K_);              \
                     float pr = 1.f / pk;                         \
                     float f  = row[K_];                          \
                     bool piv = (r == K_);                        \
                     float t  = piv ? -pr : f * pr;               \
                     GJ_C64                                        \
                     row[K_] = -t; }
#define GJ_S4(k)  GJ_STEP(k) GJ_STEP((k)+1) GJ_STEP((k)+2) GJ_STEP((k)+3)
#define GJ_S16(k) GJ_S4(k) GJ_S4((k)+4) GJ_S4((k)+8) GJ_S4((k)+12)
#define GJ_S64    GJ_S16(0) GJ_S16(16) GJ_S16(32) GJ_S16(48)

__global__ __launch_bounds__(64, 1) void gj_dinv_k(const float* __restrict__ W, float* __restrict__ Dinv, int k0){
  int b = blockIdx.x;
  int r = threadIdx.x;
  const float* Wb = W + (long)b * TT * TT + (long)(k0 + r) * TT + k0;
  float row[64];
#pragma unroll
  for (int c = 0; c < 64; c += 4) {
    float4 v = ld4(Wb + c);
    row[c] = v.x; row[c+1] = v.y; row[c+2] = v.z; row[c+3] = v.w;
  }
  GJ_S64
  float* Db = Dinv + b * 4096 + r * 64;
#pragma unroll
  for (int c = 0; c < 64; c += 4) {
    float4 v; v.x = row[c]; v.y = row[c+1]; v.z = row[c+2]; v.w = row[c+3];
    *(float4*)(Db + c) = v;
  }
}

// ---------------- GJ: fused {Rnew = Dinv @ W[K,:] (cols K := Dinv)} + {Cold = W[:,K]} ----------------
__global__ __launch_bounds__(256) void gj_prep_k(const float* __restrict__ W, const float* __restrict__ Dinv,
                                                 float* __restrict__ Cold, float* __restrict__ Rnew, int k0){
  int b = blockIdx.y;
  int bx = blockIdx.x;
  if (bx < 256) {
    const float* Wb = W + (long)b * TT * TT;
    const float* Db = Dinv + b * 4096;
    int idx = bx * 256 + threadIdx.x;
    int p = idx >> 10, j = idx & 1023;
    float acc = 0.f;
    for (int q = 0; q < 64; ++q) acc = fmaf(Db[p * 64 + q], Wb[(long)(k0 + q) * TT + j], acc);
    if (j >= k0 && j < k0 + NB) acc = Db[p * 64 + (j - k0)];
    Rnew[(long)b * 65536 + idx] = acc;
  } else {
    int idx = (bx - 256) * 256 + threadIdx.x;
    int i = idx >> 6, q = idx & 63;
    Cold[(long)b * 65536 + idx] = W[(long)b * TT * TT + (long)i * TT + k0 + q];
  }
}

// ---------------- d0, diag, df[:,0] ----------------
__global__ void ddiag_k(const float* __restrict__ W, const float* __restrict__ fi,
                        float* __restrict__ d0, float* __restrict__ diag, float* __restrict__ dfout){
  int t = blockIdx.x * 256 + threadIdx.x;
  int b = t >> 10, i = t & 1023;
  const float* Wb = W + (long)b * TT * TT;
  float dv = fi[t] * Wb[(long)i * TT];
  d0[t] = dv;
  diag[t] = Wb[(long)i * TT + i];
  dfout[(long)b * TT * 1025 + (long)i * 1025] = dv;
}

// ---------------- dx (in-place over A) + transposed df store ----------------
__global__ __launch_bounds__(256) void dx_k(float* __restrict__ A, const float* __restrict__ W,
                                            const float* __restrict__ diag, float* __restrict__ dfout){
  int b = blockIdx.z;
  int i0 = blockIdx.y * 64, j0 = blockIdx.x * 64;
  const float* Wb = W + (long)b * TT * TT;
  float* Ab = A + (long)b * TT * TT;
  __shared__ float Ls[64][65];
  __shared__ float Sx[64][65];
  int tid = threadIdx.x;
  for (int idx = tid; idx < 4096; idx += 256) {
    int r = idx >> 6, c = idx & 63;
    Ls[r][c] = Wb[(long)(j0 + r) * TT + i0 + c];   // LLinv[j][i] tile
  }
  __syncthreads();
  for (int idx = tid; idx < 4096; idx += 256) {
    int r = idx >> 6, c = idx & 63;
    int i = i0 + r, j = j0 + c;
    float a = Ab[(long)i * TT + j];
    float v = 0.f;
    if (j > 0) v = a * diag[b * TT + j];
    if (i > 0) v -= a * Ls[c][r];
    Ab[(long)i * TT + j] = v;
    Sx[r][c] = v;
  }
  __syncthreads();
  float* dfb = dfout + (long)b * TT * 1025;
  for (int idx = tid; idx < 4096; idx += 256) {
    int r = idx >> 6, c = idx & 63;
    dfb[(long)(j0 + r) * 1025 + i0 + 1 + c] = Sx[c][r];   // df[t=j][k=i+1] = dx[i][j]
  }
}

// ---------------- concat [sem | pinp | cinp] ----------------
__global__ void concat_k(const float* __restrict__ sem, const float* __restrict__ pinp,
                         const float* __restrict__ cinp, float* __restrict__ finp){
  long idx = ((long)blockIdx.x * 256 + threadIdx.x) << 2;
  long row = idx / 1536; int col = (int)(idx % 1536);
  float4 v;
  if (col < 512)       v = ld4(sem  + row * 512 + col);
  else if (col < 1024) v = ld4(pinp + row * 512 + (col - 512));
  else                 v = ld4(cinp + row * 512 + (col - 1024));
  *(float4*)(finp + idx) = v;
}

extern "C" void kernel_launch(void* const* d_in, const int* in_sizes, int n_in,
                              void* d_out, int out_size, void* d_ws, size_t ws_size,
                              hipStream_t stream){
  const float* input   = (const float*)d_in[0];
  const float* Wtp     = (const float*)d_in[1];
  const float* btp     = (const float*)d_in[2];
  const float* Wtc     = (const float*)d_in[3];
  const float* btc     = (const float*)d_in[4];
  const float* wfi     = (const float*)d_in[5];
  const float* Wbil    = (const float*)d_in[6];
  const float* exparam = (const float*)d_in[7];
  const float* Wfz     = (const float*)d_in[8];
  const float* bfz     = (const float*)d_in[9];

  if (ws_size < 156000000UL) return;   // need ~148.3 MB of scratch

  float* ws   = (float*)d_ws;
  float* sem  = ws;                 // 8192*512
  float* strv = ws + 4194304;       // 8192*512
  float* tp   = ws + 8388608;       // 8192*512
  float* tc   = ws + 12582912;      // 8192*512
  float* tpw  = ws + 16777216;      // 8192*512
  float* Abuf = ws + 20971520;      // 8*1024*1024  (later dx in-place, then finp reuse)
  float* Wbuf = ws + 29360128;      // 8*1024*1024  (becomes LLinv)
  float* fi   = ws + 37748736;      // 8192
  float* cs   = ws + 37756928;      // 8192
  float* d0   = ws + 37765120;      // 8192
  float* dg   = ws + 37773312;      // 8192
  float* Dinv = ws + 37781504;      // 8*64*64
  float* Cold = ws + 37814272;      // 8*1024*64
  float* Rnew = ws + 38338560;      // 8*64*1024
  float* finp = Abuf;               // 8192*1536, overlaps dead Abuf/Wbuf

  float* outp = (float*)d_out;          // 8192*512
  float* dfp  = outp + 4194304;         // 8192*1025

  split_k<<<8192, 256, 0, stream>>>(input, sem, strv);
  gemm_k<1,0,1><<<dim3(8,128,1),256,0,stream>>>(strv, Wtp, tp, 512, 512, 512, 512, 0,0,0, btp, nullptr,0,nullptr,0);
  gemm_k<1,0,1><<<dim3(8,128,1),256,0,stream>>>(strv, Wtc, tc, 512, 512, 512, 512, 0,0,0, btc, nullptr,0,nullptr,0);
  fi_k<<<2048,256,0,stream>>>(strv, wfi, fi);
  gemm_k<0,0,0><<<dim3(8,128,1),256,0,stream>>>(tp, Wbil, tpw, 512, 512, 512, 512, 0,0,0, nullptr, nullptr,0,nullptr,0);
  gemm_k<2,0,1><<<dim3(16,16,8),256,0,stream>>>(tpw, tc, Abuf, 512, 512, 512, 1024, 524288, 524288, 1048576, nullptr, nullptr,0,nullptr,0);
  colsum_k<<<dim3(4,8),256,0,stream>>>(Abuf, cs);
  buildw_k<<<32768,256,0,stream>>>(Abuf, fi, cs, Wbuf);
  // blocked in-place Gauss-Jordan inverse (no pivoting), 16 block steps
  for (int k0 = 0; k0 < TT; k0 += NB) {
    gj_dinv_k<<<8,64,0,stream>>>(Wbuf, Dinv, k0);
    gj_prep_k<<<dim3(512,8),256,0,stream>>>(Wbuf, Dinv, Cold, Rnew, k0);
    gemm_k<5,0,0><<<dim3(16,16,8),256,0,stream>>>(Cold, Rnew, Wbuf, 64, 64, 1024, 1024, 65536, 65536, 1048576, nullptr, Rnew, 65536, nullptr, k0);
  }
  ddiag_k<<<32,256,0,stream>>>(Wbuf, fi, d0, dg, dfp);
  dx_k<<<dim3(16,16,8),256,0,stream>>>(Abuf, Wbuf, dg, dfp);
  gemm_k<4,1,0><<<dim3(8,16,8),256,0,stream>>>(Abuf, sem, strv, 1024, 1024, 512, 512, 1048576, 524288, 524288, nullptr, d0, 1024, exparam, 0);
  gemm_k<0,0,0><<<dim3(8,16,8),256,0,stream>>>(Abuf, sem, tp, 1024, 1024, 512, 512, 1048576, 524288, 524288, nullptr, nullptr,0,nullptr,0);
  concat_k<<<12288,256,0,stream>>>(sem, strv, tp, finp);
  gemm_k<3,0,1><<<dim3(8,128,1),256,0,stream>>>(finp, Wfz, outp, 1536, 1536, 1536, 512, 0,0,0, bfz, nullptr,0,nullptr,0);
}

// Round 4
// 1523.258 us; speedup vs baseline: 3.9376x; 1.3751x over previous
//
#include <hip/hip_runtime.h>
#include <math.h>

#define TT 1024
#define NB 64

typedef float f32x4 __attribute__((ext_vector_type(4)));
typedef __bf16 bf16x8 __attribute__((ext_vector_type(8)));

__device__ __forceinline__ float4 ld4(const float* p){ return *(const float4*)p; }
__device__ __forceinline__ float rdlane(float v, int lane){
  return __int_as_float(__builtin_amdgcn_readlane(__float_as_int(v), lane));
}
__device__ __forceinline__ unsigned short bf16rne(float x){
  unsigned u = __float_as_uint(x);
  return (unsigned short)((u + 0x7FFF + ((u >> 16) & 1)) >> 16);
}

// ================= bf16 MFMA GEMM: C = epi(A @ B^T_panels) =================
// A: M x K bf16 row-major (lda). B: N x K bf16 row-major (ldb)  [i.e. B^T given].
// C: f32 (OUTBF=0) or bf16 (OUTBF=1), ldc. Tile 128x128, BK=32, 4 waves.
template<int EPI, int OUTBF>
__global__ __launch_bounds__(256)
void mgemm_k(const unsigned short* __restrict__ A, const unsigned short* __restrict__ B,
             void* __restrict__ Cv, int K, int lda, int ldb, int ldc,
             long sA, long sB, long sC,
             const float* __restrict__ bias,
             const float* __restrict__ e1, long sE1, const float* __restrict__ e2)
{
  const int bz = blockIdx.z;
  A += (long)bz * sA; B += (long)bz * sB;
  __shared__ char lds[16384];
  char* As = lds; char* Bs = lds + 8192;
  const int tid = threadIdx.x;
  const int l = tid & 63, wid = tid >> 6;
  const int wr = wid >> 1, wc = wid & 1;
  const int m0 = blockIdx.y * 128, n0 = blockIdx.x * 128;
  const int lrow = l & 15, lslot = (l >> 4) << 4;
  f32x4 acc[4][4] = {};

  for (int kk = 0; kk < K; kk += 32) {
#pragma unroll
    for (int i = 0; i < 2; ++i) {
      int idx = i * 256 + tid;
      int row = idx >> 2, c16 = (idx & 3) << 4;           // byte col within 64B row
      int sw = c16 ^ (((row >> 1) & 3) << 4);
      uint4 va = *(const uint4*)(A + (long)(m0 + row) * lda + kk + (c16 >> 1));
      *(uint4*)(As + row * 64 + sw) = va;
      uint4 vb = *(const uint4*)(B + (long)(n0 + row) * ldb + kk + (c16 >> 1));
      *(uint4*)(Bs + row * 64 + sw) = vb;
    }
    __syncthreads();
    bf16x8 af[4], bfr[4];
#pragma unroll
    for (int t = 0; t < 4; ++t) {
      int ra = wr * 64 + t * 16 + lrow;
      af[t]  = *(const bf16x8*)(As + ra * 64 + (lslot ^ (((ra >> 1) & 3) << 4)));
      int rb = wc * 64 + t * 16 + lrow;
      bfr[t] = *(const bf16x8*)(Bs + rb * 64 + (lslot ^ (((rb >> 1) & 3) << 4)));
    }
#pragma unroll
    for (int mi = 0; mi < 4; ++mi)
#pragma unroll
      for (int ni = 0; ni < 4; ++ni)
        acc[mi][ni] = __builtin_amdgcn_mfma_f32_16x16x32_bf16(af[mi], bfr[ni], acc[mi][ni], 0, 0, 0);
    __syncthreads();
  }

  float* Cf = (float*)Cv; unsigned short* Cb = (unsigned short*)Cv;
  if (OUTBF) Cb += (long)bz * sC; else Cf += (long)bz * sC;
  if (e1) e1 += (long)bz * sE1;
#pragma unroll
  for (int mi = 0; mi < 4; ++mi)
#pragma unroll
  for (int ni = 0; ni < 4; ++ni)
#pragma unroll
  for (int r = 0; r < 4; ++r) {
    int m = m0 + wr * 64 + mi * 16 + ((l >> 4) << 2) + r;
    int n = n0 + wc * 64 + ni * 16 + (l & 15);
    float v = acc[mi][ni][r];
    if (EPI == 1) v = tanhf(v + bias[n]);
    else if (EPI == 2) v = (m == n) ? 0.f : expf(tanhf(v));
    else if (EPI == 3) v = fmaxf(v + bias[n], 0.f);
    else if (EPI == 4) v = v + e1[m] * e2[n];
    if (OUTBF) Cb[(long)m * ldc + n] = bf16rne(v);
    else       Cf[(long)m * ldc + n] = v;
  }
}

// ---------------- fp32 GEMM (kept ONLY for the GJ trailing update, EPI5) ----------------
template<int EPI>
__global__ __launch_bounds__(256)
void gemm_k(const float* __restrict__ A, const float* __restrict__ B,
            float* __restrict__ C, int K, int lda, int ldb, int ldc,
            long sA, long sB, long sC,
            const float* __restrict__ e1, int k0p)
{
  const int bz = blockIdx.z;
  A += (long)bz * sA; B += (long)bz * sB; C += (long)bz * sC;
  if (e1) e1 += (long)bz * 65536;
  __shared__ float As[16][68];
  __shared__ float Bs[16][68];
  const int m0 = blockIdx.y * 64, n0 = blockIdx.x * 64;
  const int tid = threadIdx.x;
  const int tx = tid & 15, ty = tid >> 4;
  float acc[4][4] = {};
  for (int kk = 0; kk < K; kk += 16) {
    {
      int row = tid >> 2, kq = (tid & 3) << 2;
      float4 v = ld4(A + (long)(m0 + row) * lda + kk + kq);
      As[kq+0][row] = v.x; As[kq+1][row] = v.y; As[kq+2][row] = v.z; As[kq+3][row] = v.w;
    }
    {
      int k = tid >> 4, nq = (tid & 15) << 2;
      *(float4*)&Bs[k][nq] = ld4(B + (long)(kk + k) * ldb + n0 + nq);
    }
    __syncthreads();
#pragma unroll
    for (int k = 0; k < 16; ++k) {
      float a[4], b[4];
      *(float4*)a = *(const float4*)&As[k][ty << 2];
      *(float4*)b = *(const float4*)&Bs[k][tx << 2];
#pragma unroll
      for (int i = 0; i < 4; ++i)
#pragma unroll
        for (int j = 0; j < 4; ++j) acc[i][j] = fmaf(a[i], b[j], acc[i][j]);
    }
    __syncthreads();
  }
#pragma unroll
  for (int i = 0; i < 4; ++i) {
    int m = m0 + (ty << 2) + i;
#pragma unroll
    for (int j = 0; j < 4; ++j) {
      int n = n0 + (tx << 2) + j;
      float v = acc[i][j];
      float* cp = C + (long)m * ldc + n;
      bool rowK = (m >= k0p && m < k0p + NB);
      bool colK = (n >= k0p && n < k0p + NB);
      float out;
      if (rowK) out = e1[(long)(m - k0p) * TT + n];
      else      out = (colK ? 0.f : *cp) - v;
      *cp = out;
    }
  }
}

// ---------------- feature split ----------------
__global__ void split_k(const float* __restrict__ in, float* __restrict__ sem, float* __restrict__ str){
  long row = blockIdx.x;
  int c = threadIdx.x << 2;
  float4 v = ld4(in + row * 1024 + c);
  float* dst;
  if (c < 256)      dst = sem + row * 512 + c;
  else if (c < 512) dst = str + row * 512 + (c - 256);
  else if (c < 768) dst = sem + row * 512 + 256 + (c - 512);
  else              dst = str + row * 512 + 256 + (c - 768);
  *(float4*)dst = v;
}

// ---------------- casts ----------------
__global__ void castrow_k(const float* __restrict__ src, unsigned short* __restrict__ dst){
  long i = ((long)blockIdx.x * 256 + threadIdx.x) << 2;
  float4 v = ld4(src + i);
  unsigned lo = bf16rne(v.x) | ((unsigned)bf16rne(v.y) << 16);
  unsigned hi = bf16rne(v.z) | ((unsigned)bf16rne(v.w) << 16);
  uint2 w; w.x = lo; w.y = hi;
  *(uint2*)(dst + i) = w;
}

// transpose+cast: src f32 [R][C] -> dst bf16 [C][R], per batch
__global__ __launch_bounds__(256) void castT_k(const float* __restrict__ src, unsigned short* __restrict__ dst,
                                               int R, int C, long sS, long sD){
  int b = blockIdx.z;
  src += (long)b * sS; dst += (long)b * sD;
  __shared__ float t[32][33];
  int r0 = blockIdx.y * 32, c0 = blockIdx.x * 32;
  int tx = threadIdx.x & 31, ty = threadIdx.x >> 5;
#pragma unroll
  for (int j = 0; j < 32; j += 8)
    t[ty + j][tx] = src[(long)(r0 + ty + j) * C + c0 + tx];
  __syncthreads();
#pragma unroll
  for (int j = 0; j < 32; j += 8)
    dst[(long)(c0 + ty + j) * R + r0 + tx] = bf16rne(t[tx][ty + j]);
}

// sem f32 -> finpb cols [0,512) bf16
__global__ void semcopy_k(const float* __restrict__ sem, unsigned short* __restrict__ finpb){
  long idx = ((long)blockIdx.x * 256 + threadIdx.x) << 2;
  long row = idx >> 9; int col = (int)(idx & 511);
  float4 v = ld4(sem + idx);
  unsigned lo = bf16rne(v.x) | ((unsigned)bf16rne(v.y) << 16);
  unsigned hi = bf16rne(v.z) | ((unsigned)bf16rne(v.w) << 16);
  uint2 w; w.x = lo; w.y = hi;
  *(uint2*)(finpb + row * 1536 + col) = w;
}

// ---------------- f_i = exp(tanh(str . wfi)) ----------------
__global__ void fi_k(const float* __restrict__ str, const float* __restrict__ wfi, float* __restrict__ fi){
  int row = blockIdx.x * 4 + (threadIdx.x >> 6);
  int lane = threadIdx.x & 63;
  const float* p = str + (long)row * 512;
  float acc = 0.f;
  for (int c = lane; c < 512; c += 64) acc = fmaf(p[c], wfi[c], acc);
  for (int off = 32; off; off >>= 1) acc += __shfl_down(acc, off, 64);
  if (lane == 0) fi[row] = expf(tanhf(acc));
}

// ---------------- column sums ----------------
__global__ void colsum_k(const float* __restrict__ A, float* __restrict__ cs){
  int b = blockIdx.y;
  int j = blockIdx.x * 256 + threadIdx.x;
  const float* p = A + (long)b * TT * TT + j;
  float acc = 0.f;
  for (int i = 0; i < TT; ++i) acc += p[(long)i * TT];
  cs[b * TT + j] = acc;
}

// ---------------- build L_bar ----------------
__global__ void buildw_k(const float* __restrict__ A, const float* __restrict__ fi,
                         const float* __restrict__ cs, float* __restrict__ W){
  long idx = (long)blockIdx.x * 256 + threadIdx.x;
  long b = idx >> 20;
  long r = idx & 1048575;
  int i = (int)(r >> 10), j = (int)(r & 1023);
  float v;
  if (i == 0)      v = fi[b * TT + j];
  else if (i == j) v = cs[b * TT + j];
  else             v = -A[idx];
  W[idx] = v;
}

// ---------------- GJ: 64x64 diag-block inverse, register-resident ----------------
#define GJ_COL(c) { float bc = rdlane(row[(c)], (K_));            \
                    float z  = piv ? 0.f : row[(c)];              \
                    row[(c)] = fmaf(-t, bc, z); }
#define GJ_C4(c)  GJ_COL(c) GJ_COL((c)+1) GJ_COL((c)+2) GJ_COL((c)+3)
#define GJ_C16(c) GJ_C4(c) GJ_C4((c)+4) GJ_C4((c)+8) GJ_C4((c)+12)
#define GJ_C64    GJ_C16(0) GJ_C16(16) GJ_C16(32) GJ_C16(48)
#define GJ_STEP(k) { enum { K_ = (k) };                           \
                     float pk = rdlane(row[K_], K_);              \
                     float pr = 1.f / pk;                         \
                     float f  = row[K_];                          \
                     bool piv = (r == K_);                        \
                     float t  = piv ? -pr : f * pr;               \
                     GJ_C64                                        \
                     row[K_] = -t; }
#define GJ_S4(k)  GJ_STEP(k) GJ_STEP((k)+1) GJ_STEP((k)+2) GJ_STEP((k)+3)
#define GJ_S16(k) GJ_S4(k) GJ_S4((k)+4) GJ_S4((k)+8) GJ_S4((k)+12)
#define GJ_S64    GJ_S16(0) GJ_S16(16) GJ_S16(32) GJ_S16(48)

__global__ __launch_bounds__(64, 1) void gj_dinv_k(const float* __restrict__ W, float* __restrict__ Dinv, int k0){
  int b = blockIdx.x;
  int r = threadIdx.x;
  const float* Wb = W + (long)b * TT * TT + (long)(k0 + r) * TT + k0;
  float row[64];
#pragma unroll
  for (int c = 0; c < 64; c += 4) {
    float4 v = ld4(Wb + c);
    row[c] = v.x; row[c+1] = v.y; row[c+2] = v.z; row[c+3] = v.w;
  }
  GJ_S64
  float* Db = Dinv + b * 4096 + r * 64;
#pragma unroll
  for (int c = 0; c < 64; c += 4) {
    float4 v; v.x = row[c]; v.y = row[c+1]; v.z = row[c+2]; v.w = row[c+3];
    *(float4*)(Db + c) = v;
  }
}

// ---------------- GJ: fused {Rnew = Dinv @ W[K,:] (cols K := Dinv)} + {Cold = W[:,K]} ----------------
__global__ __launch_bounds__(256) void gj_prep_k(const float* __restrict__ W, const float* __restrict__ Dinv,
                                                 float* __restrict__ Cold, float* __restrict__ Rnew, int k0){
  int b = blockIdx.y;
  int bx = blockIdx.x;
  if (bx < 256) {
    const float* Wb = W + (long)b * TT * TT;
    const float* Db = Dinv + b * 4096;
    int idx = bx * 256 + threadIdx.x;
    int p = idx >> 10, j = idx & 1023;
    float acc = 0.f;
    for (int q = 0; q < 64; ++q) acc = fmaf(Db[p * 64 + q], Wb[(long)(k0 + q) * TT + j], acc);
    if (j >= k0 && j < k0 + NB) acc = Db[p * 64 + (j - k0)];
    Rnew[(long)b * 65536 + idx] = acc;
  } else {
    int idx = (bx - 256) * 256 + threadIdx.x;
    int i = idx >> 6, q = idx & 63;
    Cold[(long)b * 65536 + idx] = W[(long)b * TT * TT + (long)i * TT + k0 + q];
  }
}

// ---------------- d0, diag, df col 0 ----------------
__global__ void ddiag_k(const float* __restrict__ W, const float* __restrict__ fi,
                        float* __restrict__ d0, float* __restrict__ diag, float* __restrict__ dfout){
  int t = blockIdx.x * 256 + threadIdx.x;
  int b = t >> 10, i = t & 1023;
  const float* Wb = W + (long)b * TT * TT;
  float dv = fi[t] * Wb[(long)i * TT];
  d0[t] = dv;
  diag[t] = Wb[(long)i * TT + i];
  dfout[(long)b * TT * 1025 + (long)i * 1025] = dv;
}

// ---------------- dx: compute, emit bf16 dx + bf16 dx^T + df store ----------------
__global__ __launch_bounds__(256) void dx_k(const float* __restrict__ A, const float* __restrict__ W,
                                            const float* __restrict__ diag, float* __restrict__ dfout,
                                            unsigned short* __restrict__ dxb, unsigned short* __restrict__ dxTb){
  int b = blockIdx.z;
  int i0 = blockIdx.y * 64, j0 = blockIdx.x * 64;
  const float* Wb = W + (long)b * TT * TT;
  const float* Ab = A + (long)b * TT * TT;
  __shared__ float Ls[64][65];
  __shared__ float Sx[64][65];
  int tid = threadIdx.x;
  for (int idx = tid; idx < 4096; idx += 256) {
    int r = idx >> 6, c = idx & 63;
    Ls[r][c] = Wb[(long)(j0 + r) * TT + i0 + c];   // LLinv[j][i] tile
  }
  __syncthreads();
  for (int idx = tid; idx < 4096; idx += 256) {
    int r = idx >> 6, c = idx & 63;
    int i = i0 + r, j = j0 + c;
    float a = Ab[(long)i * TT + j];
    float v = 0.f;
    if (j > 0) v = a * diag[b * TT + j];
    if (i > 0) v -= a * Ls[c][r];
    dxb[(long)b * 1048576 + (long)i * 1024 + j] = bf16rne(v);
    Sx[r][c] = v;
  }
  __syncthreads();
  float* dfb = dfout + (long)b * TT * 1025;
  unsigned short* dtb = dxTb + (long)b * 1048576;
  for (int idx = tid; idx < 4096; idx += 256) {
    int r = idx >> 6, c = idx & 63;
    float v = Sx[c][r];
    dfb[(long)(j0 + r) * 1025 + i0 + 1 + c] = v;     // df[t=j][k=i+1]
    dtb[(long)(j0 + r) * 1024 + i0 + c] = bf16rne(v); // dxT[j][i]
  }
}

extern "C" void kernel_launch(void* const* d_in, const int* in_sizes, int n_in,
                              void* d_out, int out_size, void* d_ws, size_t ws_size,
                              hipStream_t stream){
  const float* input   = (const float*)d_in[0];
  const float* Wtp     = (const float*)d_in[1];
  const float* btp     = (const float*)d_in[2];
  const float* Wtc     = (const float*)d_in[3];
  const float* btc     = (const float*)d_in[4];
  const float* wfi     = (const float*)d_in[5];
  const float* Wbil    = (const float*)d_in[6];
  const float* exparam = (const float*)d_in[7];
  const float* Wfz     = (const float*)d_in[8];
  const float* bfz     = (const float*)d_in[9];

  if (ws_size < 142000000UL) return;

  float* ws   = (float*)d_ws;
  float* sem   = ws;                    // 4,194,304 f
  float* strv  = ws + 4194304;          // 4,194,304 f  [later: dxb bf16]
  float* Abuf  = ws + 8388608;          // 8,388,608 f  [later: finpb bf16]
  float* Wbuf  = ws + 16777216;         // 8,388,608 f
  unsigned short* strb = (unsigned short*)(ws + 25165824);  // 4,194,304 bf16
  unsigned short* tpb  = (unsigned short*)(ws + 27262976);  // 4,194,304 bf16
  unsigned short* tcb  = (unsigned short*)(ws + 29360128);  // 4,194,304 bf16 [later: semTb]
  unsigned short* tpwb = (unsigned short*)(ws + 31457280);  // 4,194,304 bf16
  unsigned short* wtpb = (unsigned short*)(ws + 33554432);  // 262,144 bf16
  unsigned short* wtcb = (unsigned short*)(ws + 33685504);
  unsigned short* wbilT= (unsigned short*)(ws + 33816576);
  unsigned short* wfzb = (unsigned short*)(ws + 33947648);  // 786,432 bf16
  float* fi    = ws + 34340864;
  float* cs    = ws + 34349056;
  float* d0    = ws + 34357248;
  float* dg    = ws + 34365440;
  float* Dinv  = ws + 34373632;         // 32,768 f
  float* Cold  = ws + 34406400;         // 524,288 f
  float* Rnew  = ws + 34930688;         // 524,288 f
  // aliases (timeline-checked)
  unsigned short* dxb   = (unsigned short*)strv;            // after fi_k
  unsigned short* dxTb  = (unsigned short*)(ws + 25165824); // over strb+tpb (dead)
  unsigned short* semTb = (unsigned short*)(ws + 29360128); // over tcb (dead after A-score)
  unsigned short* finpb = (unsigned short*)Abuf;            // after dx_k

  float* outp = (float*)d_out;          // 8192*512
  float* dfp  = outp + 4194304;         // 8192*1025

  split_k<<<8192, 256, 0, stream>>>(input, sem, strv);
  castrow_k<<<4096, 256, 0, stream>>>(strv, strb);
  castrow_k<<<256, 256, 0, stream>>>(Wtp, wtpb);
  castrow_k<<<256, 256, 0, stream>>>(Wtc, wtcb);
  castrow_k<<<768, 256, 0, stream>>>(Wfz, wfzb);
  castT_k<<<dim3(16,16,1), 256, 0, stream>>>(Wbil, wbilT, 512, 512, 0, 0);
  fi_k<<<2048, 256, 0, stream>>>(strv, wfi, fi);
  // tp = tanh(str@Wtp^T+b) -> bf16 ; tc likewise
  mgemm_k<1,1><<<dim3(4,64,1),256,0,stream>>>(strb, wtpb, tpb, 512, 512, 512, 512, 0,0,0, btp, nullptr,0,nullptr);
  mgemm_k<1,1><<<dim3(4,64,1),256,0,stream>>>(strb, wtcb, tcb, 512, 512, 512, 512, 0,0,0, btc, nullptr,0,nullptr);
  // tpw = tp @ Wbil -> bf16
  mgemm_k<0,1><<<dim3(4,64,1),256,0,stream>>>(tpb, wbilT, tpwb, 512, 512, 512, 512, 0,0,0, nullptr, nullptr,0,nullptr);
  // A = exp(tanh(tpw_b @ tc_b^T)), zero diag -> f32
  mgemm_k<2,0><<<dim3(8,8,8),256,0,stream>>>(tpwb, tcb, Abuf, 512, 512, 512, 1024, 524288,524288,1048576, nullptr, nullptr,0,nullptr);
  // semT (after tcb dead)
  castT_k<<<dim3(16,32,8), 256, 0, stream>>>(sem, semTb, 1024, 512, 524288, 524288);
  colsum_k<<<dim3(4,8),256,0,stream>>>(Abuf, cs);
  buildw_k<<<32768,256,0,stream>>>(Abuf, fi, cs, Wbuf);
  // blocked in-place Gauss-Jordan inverse (fp32)
  for (int k0 = 0; k0 < TT; k0 += NB) {
    gj_dinv_k<<<8,64,0,stream>>>(Wbuf, Dinv, k0);
    gj_prep_k<<<dim3(512,8),256,0,stream>>>(Wbuf, Dinv, Cold, Rnew, k0);
    gemm_k<5><<<dim3(16,16,8),256,0,stream>>>(Cold, Rnew, Wbuf, 64, 64, 1024, 1024, 65536,65536,1048576, Rnew, k0);
  }
  ddiag_k<<<32,256,0,stream>>>(Wbuf, fi, d0, dg, dfp);
  dx_k<<<dim3(16,16,8),256,0,stream>>>(Abuf, Wbuf, dg, dfp, dxb, dxTb);
  // finp = [sem | pinp | cinp] in bf16 (written directly by each producer)
  semcopy_k<<<4096,256,0,stream>>>(sem, finpb);
  // pinp = dx^T @ sem + d0 x exparam -> finpb cols [512,1024)
  mgemm_k<4,1><<<dim3(4,8,8),256,0,stream>>>(dxTb, semTb, finpb + 512, 1024, 1024, 1024, 1536,
                                             1048576, 524288, 1572864, nullptr, d0, 1024, exparam);
  // cinp = dx @ sem -> finpb cols [1024,1536)
  mgemm_k<0,1><<<dim3(4,8,8),256,0,stream>>>(dxb, semTb, finpb + 1024, 1024, 1024, 1024, 1536,
                                             1048576, 524288, 1572864, nullptr, nullptr,0,nullptr);
  // out = relu(finp @ Wfz^T + bfz) -> f32
  mgemm_k<3,0><<<dim3(4,64,1),256,0,stream>>>(finpb, wfzb, outp, 1536, 1536, 1536, 512, 0,0,0, bfz, nullptr,0,nullptr);
}

// Round 5
// 1421.808 us; speedup vs baseline: 4.2185x; 1.0714x over previous
//
#include <hip/hip_runtime.h>
#include <math.h>

#define TT 1024
#define NB 64

typedef float f32x4 __attribute__((ext_vector_type(4)));
typedef __bf16 bf16x8 __attribute__((ext_vector_type(8)));

__device__ __forceinline__ float4 ld4(const float* p){ return *(const float4*)p; }
__device__ __forceinline__ unsigned short bf16rne(float x){
  unsigned u = __float_as_uint(x);
  return (unsigned short)((u + 0x7FFF + ((u >> 16) & 1)) >> 16);
}

// ================= bf16 MFMA GEMM: C = epi(A @ B^T_panels) =================
template<int EPI, int OUTBF>
__global__ __launch_bounds__(256)
void mgemm_k(const unsigned short* __restrict__ A, const unsigned short* __restrict__ B,
             void* __restrict__ Cv, int K, int lda, int ldb, int ldc,
             long sA, long sB, long sC,
             const float* __restrict__ bias,
             const float* __restrict__ e1, long sE1, const float* __restrict__ e2)
{
  const int bz = blockIdx.z;
  A += (long)bz * sA; B += (long)bz * sB;
  __shared__ char lds[16384];
  char* As = lds; char* Bs = lds + 8192;
  const int tid = threadIdx.x;
  const int l = tid & 63, wid = tid >> 6;
  const int wr = wid >> 1, wc = wid & 1;
  const int m0 = blockIdx.y * 128, n0 = blockIdx.x * 128;
  const int lrow = l & 15, lslot = (l >> 4) << 4;
  f32x4 acc[4][4] = {};

  for (int kk = 0; kk < K; kk += 32) {
#pragma unroll
    for (int i = 0; i < 2; ++i) {
      int idx = i * 256 + tid;
      int row = idx >> 2, c16 = (idx & 3) << 4;
      int sw = c16 ^ (((row >> 1) & 3) << 4);
      uint4 va = *(const uint4*)(A + (long)(m0 + row) * lda + kk + (c16 >> 1));
      *(uint4*)(As + row * 64 + sw) = va;
      uint4 vb = *(const uint4*)(B + (long)(n0 + row) * ldb + kk + (c16 >> 1));
      *(uint4*)(Bs + row * 64 + sw) = vb;
    }
    __syncthreads();
    bf16x8 af[4], bfr[4];
#pragma unroll
    for (int t = 0; t < 4; ++t) {
      int ra = wr * 64 + t * 16 + lrow;
      af[t]  = *(const bf16x8*)(As + ra * 64 + (lslot ^ (((ra >> 1) & 3) << 4)));
      int rb = wc * 64 + t * 16 + lrow;
      bfr[t] = *(const bf16x8*)(Bs + rb * 64 + (lslot ^ (((rb >> 1) & 3) << 4)));
    }
#pragma unroll
    for (int mi = 0; mi < 4; ++mi)
#pragma unroll
      for (int ni = 0; ni < 4; ++ni)
        acc[mi][ni] = __builtin_amdgcn_mfma_f32_16x16x32_bf16(af[mi], bfr[ni], acc[mi][ni], 0, 0, 0);
    __syncthreads();
  }

  float* Cf = (float*)Cv; unsigned short* Cb = (unsigned short*)Cv;
  if (OUTBF) Cb += (long)bz * sC; else Cf += (long)bz * sC;
  if (e1) e1 += (long)bz * sE1;
#pragma unroll
  for (int mi = 0; mi < 4; ++mi)
#pragma unroll
  for (int ni = 0; ni < 4; ++ni)
#pragma unroll
  for (int r = 0; r < 4; ++r) {
    int m = m0 + wr * 64 + mi * 16 + ((l >> 4) << 2) + r;
    int n = n0 + wc * 64 + ni * 16 + (l & 15);
    float v = acc[mi][ni][r];
    if (EPI == 1) v = tanhf(v + bias[n]);
    else if (EPI == 2) v = (m == n) ? 0.f : expf(tanhf(v));
    else if (EPI == 3) v = fmaxf(v + bias[n], 0.f);
    else if (EPI == 4) v = v + e1[m] * e2[n];
    if (OUTBF) Cb[(long)m * ldc + n] = bf16rne(v);
    else       Cf[(long)m * ldc + n] = v;
  }
}

// ---------------- feature split ----------------
__global__ void split_k(const float* __restrict__ in, float* __restrict__ sem, float* __restrict__ str){
  long row = blockIdx.x;
  int c = threadIdx.x << 2;
  float4 v = ld4(in + row * 1024 + c);
  float* dst;
  if (c < 256)      dst = sem + row * 512 + c;
  else if (c < 512) dst = str + row * 512 + (c - 256);
  else if (c < 768) dst = sem + row * 512 + 256 + (c - 512);
  else              dst = str + row * 512 + 256 + (c - 768);
  *(float4*)dst = v;
}

// ---------------- casts ----------------
__global__ void castrow_k(const float* __restrict__ src, unsigned short* __restrict__ dst){
  long i = ((long)blockIdx.x * 256 + threadIdx.x) << 2;
  float4 v = ld4(src + i);
  unsigned lo = bf16rne(v.x) | ((unsigned)bf16rne(v.y) << 16);
  unsigned hi = bf16rne(v.z) | ((unsigned)bf16rne(v.w) << 16);
  uint2 w; w.x = lo; w.y = hi;
  *(uint2*)(dst + i) = w;
}

__global__ __launch_bounds__(256) void castT_k(const float* __restrict__ src, unsigned short* __restrict__ dst,
                                               int R, int C, long sS, long sD){
  int b = blockIdx.z;
  src += (long)b * sS; dst += (long)b * sD;
  __shared__ float t[32][33];
  int r0 = blockIdx.y * 32, c0 = blockIdx.x * 32;
  int tx = threadIdx.x & 31, ty = threadIdx.x >> 5;
#pragma unroll
  for (int j = 0; j < 32; j += 8)
    t[ty + j][tx] = src[(long)(r0 + ty + j) * C + c0 + tx];
  __syncthreads();
#pragma unroll
  for (int j = 0; j < 32; j += 8)
    dst[(long)(c0 + ty + j) * R + r0 + tx] = bf16rne(t[tx][ty + j]);
}

__global__ void semcopy_k(const float* __restrict__ sem, unsigned short* __restrict__ finpb){
  long idx = ((long)blockIdx.x * 256 + threadIdx.x) << 2;
  long row = idx >> 9; int col = (int)(idx & 511);
  float4 v = ld4(sem + idx);
  unsigned lo = bf16rne(v.x) | ((unsigned)bf16rne(v.y) << 16);
  unsigned hi = bf16rne(v.z) | ((unsigned)bf16rne(v.w) << 16);
  uint2 w; w.x = lo; w.y = hi;
  *(uint2*)(finpb + row * 1536 + col) = w;
}

// ---------------- f_i = exp(tanh(str . wfi)) ----------------
__global__ void fi_k(const float* __restrict__ str, const float* __restrict__ wfi, float* __restrict__ fi){
  int row = blockIdx.x * 4 + (threadIdx.x >> 6);
  int lane = threadIdx.x & 63;
  const float* p = str + (long)row * 512;
  float acc = 0.f;
  for (int c = lane; c < 512; c += 64) acc = fmaf(p[c], wfi[c], acc);
  for (int off = 32; off; off >>= 1) acc += __shfl_down(acc, off, 64);
  if (lane == 0) fi[row] = expf(tanhf(acc));
}

// ---------------- column sums ----------------
__global__ void colsum_k(const float* __restrict__ A, float* __restrict__ cs){
  int b = blockIdx.y;
  int j = blockIdx.x * 256 + threadIdx.x;
  const float* p = A + (long)b * TT * TT + j;
  float acc = 0.f;
  for (int i = 0; i < TT; ++i) acc += p[(long)i * TT];
  cs[b * TT + j] = acc;
}

// ---------------- build L_bar (+ emit Cold0 = W[:, 0:64]) ----------------
__global__ void buildw_k(const float* __restrict__ A, const float* __restrict__ fi,
                         const float* __restrict__ cs, float* __restrict__ W,
                         float* __restrict__ Cold0){
  long idx = (long)blockIdx.x * 256 + threadIdx.x;
  long b = idx >> 20;
  long r = idx & 1048575;
  int i = (int)(r >> 10), j = (int)(r & 1023);
  float v;
  if (i == 0)      v = fi[b * TT + j];
  else if (i == j) v = cs[b * TT + j];
  else             v = -A[idx];
  W[idx] = v;
  if (j < 64) Cold0[b * 65536 + i * 64 + j] = v;
}

// ---------------- GJ: 64x64 diag-block inverse, LDS-resident, 256 thr ----------------
// thread (r = tid&63, q = tid>>6) owns cols [16q,16q+16) of row r.
__global__ __launch_bounds__(256, 1) void gj_dinv_k(const float* __restrict__ W, float* __restrict__ Dinv, int k0){
  __shared__ float P[64][68];
  int b = blockIdx.x;
  int tid = threadIdx.x;
  int r = tid & 63, q = tid >> 6;
  int q16 = q << 4;
  const float* Wb = W + (long)b * TT * TT + (long)(k0 + r) * TT + k0 + q16;
#pragma unroll
  for (int j = 0; j < 16; j += 4) *(float4*)&P[r][q16 + j] = ld4(Wb + j);
  __syncthreads();
  for (int k = 0; k < 64; ++k) {
    float pk = P[k][k];
    float f  = P[r][k];
    float pv[16], ov[16];
#pragma unroll
    for (int j = 0; j < 16; j += 4) {
      *(float4*)&pv[j] = *(float4*)&P[k][q16 + j];
      *(float4*)&ov[j] = *(float4*)&P[r][q16 + j];
    }
    __syncthreads();
    float pr = 1.f / pk;
    bool piv = (r == k);
    float t = piv ? -pr : f * pr;
#pragma unroll
    for (int c = 0; c < 16; ++c) {
      float z = piv ? 0.f : ov[c];
      float val = fmaf(-t, pv[c], z);
      if (q16 + c == k) val = -t;
      ov[c] = val;
    }
#pragma unroll
    for (int j = 0; j < 16; j += 4) *(float4*)&P[r][q16 + j] = *(float4*)&ov[j];
    __syncthreads();
  }
  float* Db = Dinv + b * 4096 + r * 64 + q16;
#pragma unroll
  for (int j = 0; j < 16; j += 4) *(float4*)(Db + j) = *(float4*)&P[r][q16 + j];
}

// ---------------- GJ: Rnew = Dinv @ W[K,:] (cols K := Dinv) ----------------
__global__ __launch_bounds__(256) void gj_prep_k(const float* __restrict__ W, const float* __restrict__ Dinv,
                                                 float* __restrict__ Rnew, int k0){
  int b = blockIdx.y;
  int p = blockIdx.x;                    // 0..63
  int j4 = threadIdx.x << 2;             // 0..1020
  const float* Wb = W + (long)b * TT * TT + (long)k0 * TT + j4;
  const float* Db = Dinv + b * 4096 + p * 64;
  float4 acc = {0.f, 0.f, 0.f, 0.f};
  for (int qq = 0; qq < 64; ++qq) {
    float d = Db[qq];
    float4 w = ld4(Wb + (long)qq * TT);
    acc.x = fmaf(d, w.x, acc.x); acc.y = fmaf(d, w.y, acc.y);
    acc.z = fmaf(d, w.z, acc.z); acc.w = fmaf(d, w.w, acc.w);
  }
  if (j4 >= k0 && j4 < k0 + NB) acc = ld4(Db + (j4 - k0));
  *(float4*)(Rnew + (long)b * 65536 + p * 1024 + j4) = acc;
}

// ---------------- GJ trailing update: W = (colK?0:W) - Cold@Rnew ; rowK rows := Rnew ----------------
// also side-writes the NEXT Cold panel (cols [k0+64, k0+128)).
__global__ __launch_bounds__(256) void gupd_k(const float* __restrict__ Cold,
                                              const float* __restrict__ Rnew,
                                              float* __restrict__ W,
                                              float* __restrict__ ColdNext, int k0){
  int b = blockIdx.z;
  const float* Ab = Cold + (long)b * 65536;   // 1024 x 64
  const float* Bb = Rnew + (long)b * 65536;   // 64 x 1024
  float* Wb = W + (long)b * 1048576;
  float* Cn = ColdNext + (long)b * 65536;
  const int m0 = blockIdx.y * 128, n0 = blockIdx.x * 128;
  const int tid = threadIdx.x;
  const int tx = tid & 15, ty = tid >> 4;
  __shared__ float As[32][132];
  __shared__ float Bs[32][132];
  float acc[8][8] = {};
  for (int kk = 0; kk < 64; kk += 32) {
#pragma unroll
    for (int rep = 0; rep < 4; ++rep) {
      int slot = rep * 256 + tid;
      int m = slot & 127, kg = slot >> 7;
      float4 v = ld4(Ab + (long)(m0 + m) * 64 + kk + (kg << 2));
      As[(kg << 2) + 0][m] = v.x; As[(kg << 2) + 1][m] = v.y;
      As[(kg << 2) + 2][m] = v.z; As[(kg << 2) + 3][m] = v.w;
      int k = slot >> 5, n4 = (slot & 31) << 2;
      float4 w = ld4(Bb + (long)(kk + k) * 1024 + n0 + n4);
      *(float4*)&Bs[k][n4] = w;
    }
    __syncthreads();
#pragma unroll
    for (int k = 0; k < 32; ++k) {
      float a[8], bb[8];
      *(float4*)&a[0]  = *(float4*)&As[k][ty << 3];
      *(float4*)&a[4]  = *(float4*)&As[k][(ty << 3) + 4];
      *(float4*)&bb[0] = *(float4*)&Bs[k][tx << 3];
      *(float4*)&bb[4] = *(float4*)&Bs[k][(tx << 3) + 4];
#pragma unroll
      for (int i = 0; i < 8; ++i)
#pragma unroll
        for (int j = 0; j < 8; ++j) acc[i][j] = fmaf(a[i], bb[j], acc[i][j]);
    }
    __syncthreads();
  }
  int g = n0 + (tx << 3);
  bool colK = (g >= k0 && g < k0 + 64);
  int cn = g - (k0 + 64);
  bool inCn = (cn >= 0 && cn < 64);
#pragma unroll
  for (int i = 0; i < 8; ++i) {
    int m = m0 + (ty << 3) + i;
    bool rowK = (m >= k0 && m < k0 + 64);
    float4 s0, s1;
    if (rowK) {
      s0 = ld4(Bb + (long)(m - k0) * 1024 + g);
      s1 = ld4(Bb + (long)(m - k0) * 1024 + g + 4);
    } else if (colK) {
      s0.x = -acc[i][0]; s0.y = -acc[i][1]; s0.z = -acc[i][2]; s0.w = -acc[i][3];
      s1.x = -acc[i][4]; s1.y = -acc[i][5]; s1.z = -acc[i][6]; s1.w = -acc[i][7];
    } else {
      float4 w0 = ld4(Wb + (long)m * 1024 + g);
      float4 w1 = ld4(Wb + (long)m * 1024 + g + 4);
      s0.x = w0.x - acc[i][0]; s0.y = w0.y - acc[i][1];
      s0.z = w0.z - acc[i][2]; s0.w = w0.w - acc[i][3];
      s1.x = w1.x - acc[i][4]; s1.y = w1.y - acc[i][5];
      s1.z = w1.z - acc[i][6]; s1.w = w1.w - acc[i][7];
    }
    *(float4*)(Wb + (long)m * 1024 + g) = s0;
    *(float4*)(Wb + (long)m * 1024 + g + 4) = s1;
    if (inCn) {
      *(float4*)(Cn + (long)m * 64 + cn) = s0;
      *(float4*)(Cn + (long)m * 64 + cn + 4) = s1;
    }
  }
}

// ---------------- d0, diag, df col 0 ----------------
__global__ void ddiag_k(const float* __restrict__ W, const float* __restrict__ fi,
                        float* __restrict__ d0, float* __restrict__ diag, float* __restrict__ dfout){
  int t = blockIdx.x * 256 + threadIdx.x;
  int b = t >> 10, i = t & 1023;
  const float* Wb = W + (long)b * TT * TT;
  float dv = fi[t] * Wb[(long)i * TT];
  d0[t] = dv;
  diag[t] = Wb[(long)i * TT + i];
  dfout[(long)b * TT * 1025 + (long)i * 1025] = dv;
}

// ---------------- dx: compute, emit bf16 dx + bf16 dx^T + df store ----------------
__global__ __launch_bounds__(256) void dx_k(const float* __restrict__ A, const float* __restrict__ W,
                                            const float* __restrict__ diag, float* __restrict__ dfout,
                                            unsigned short* __restrict__ dxb, unsigned short* __restrict__ dxTb){
  int b = blockIdx.z;
  int i0 = blockIdx.y * 64, j0 = blockIdx.x * 64;
  const float* Wb = W + (long)b * TT * TT;
  const float* Ab = A + (long)b * TT * TT;
  __shared__ float Ls[64][65];
  __shared__ float Sx[64][65];
  int tid = threadIdx.x;
  for (int idx = tid; idx < 4096; idx += 256) {
    int r = idx >> 6, c = idx & 63;
    Ls[r][c] = Wb[(long)(j0 + r) * TT + i0 + c];
  }
  __syncthreads();
  for (int idx = tid; idx < 4096; idx += 256) {
    int r = idx >> 6, c = idx & 63;
    int i = i0 + r, j = j0 + c;
    float a = Ab[(long)i * TT + j];
    float v = 0.f;
    if (j > 0) v = a * diag[b * TT + j];
    if (i > 0) v -= a * Ls[c][r];
    dxb[(long)b * 1048576 + (long)i * 1024 + j] = bf16rne(v);
    Sx[r][c] = v;
  }
  __syncthreads();
  float* dfb = dfout + (long)b * TT * 1025;
  unsigned short* dtb = dxTb + (long)b * 1048576;
  for (int idx = tid; idx < 4096; idx += 256) {
    int r = idx >> 6, c = idx & 63;
    float v = Sx[c][r];
    dfb[(long)(j0 + r) * 1025 + i0 + 1 + c] = v;
    dtb[(long)(j0 + r) * 1024 + i0 + c] = bf16rne(v);
  }
}

extern "C" void kernel_launch(void* const* d_in, const int* in_sizes, int n_in,
                              void* d_out, int out_size, void* d_ws, size_t ws_size,
                              hipStream_t stream){
  const float* input   = (const float*)d_in[0];
  const float* Wtp     = (const float*)d_in[1];
  const float* btp     = (const float*)d_in[2];
  const float* Wtc     = (const float*)d_in[3];
  const float* btc     = (const float*)d_in[4];
  const float* wfi     = (const float*)d_in[5];
  const float* Wbil    = (const float*)d_in[6];
  const float* exparam = (const float*)d_in[7];
  const float* Wfz     = (const float*)d_in[8];
  const float* bfz     = (const float*)d_in[9];

  if (ws_size < 150000000UL) return;

  float* ws   = (float*)d_ws;
  float* sem   = ws;                    // 4,194,304 f
  float* strv  = ws + 4194304;          // 4,194,304 f  [later: dxb bf16]
  float* Abuf  = ws + 8388608;          // 8,388,608 f  [later: finpb bf16]
  float* Wbuf  = ws + 16777216;         // 8,388,608 f
  unsigned short* strb = (unsigned short*)(ws + 25165824);
  unsigned short* tpb  = (unsigned short*)(ws + 27262976);
  unsigned short* tcb  = (unsigned short*)(ws + 29360128);
  unsigned short* tpwb = (unsigned short*)(ws + 31457280);
  unsigned short* wtpb = (unsigned short*)(ws + 33554432);
  unsigned short* wtcb = (unsigned short*)(ws + 33685504);
  unsigned short* wbilT= (unsigned short*)(ws + 33816576);
  unsigned short* wfzb = (unsigned short*)(ws + 33947648);
  float* fi    = ws + 34340864;
  float* cs    = ws + 34349056;
  float* d0    = ws + 34357248;
  float* dg    = ws + 34365440;
  float* Dinv  = ws + 34373632;         // 32,768 f
  float* ColdA = ws + 34406400;         // 524,288 f
  float* Rnew  = ws + 34930688;         // 524,288 f
  float* ColdB = ws + 35454976;         // 524,288 f
  unsigned short* dxb   = (unsigned short*)strv;
  unsigned short* dxTb  = (unsigned short*)(ws + 25165824);
  unsigned short* semTb = (unsigned short*)(ws + 29360128);
  unsigned short* finpb = (unsigned short*)Abuf;

  float* outp = (float*)d_out;
  float* dfp  = outp + 4194304;

  split_k<<<8192, 256, 0, stream>>>(input, sem, strv);
  castrow_k<<<4096, 256, 0, stream>>>(strv, strb);
  castrow_k<<<256, 256, 0, stream>>>(Wtp, wtpb);
  castrow_k<<<256, 256, 0, stream>>>(Wtc, wtcb);
  castrow_k<<<768, 256, 0, stream>>>(Wfz, wfzb);
  castT_k<<<dim3(16,16,1), 256, 0, stream>>>(Wbil, wbilT, 512, 512, 0, 0);
  fi_k<<<2048, 256, 0, stream>>>(strv, wfi, fi);
  mgemm_k<1,1><<<dim3(4,64,1),256,0,stream>>>(strb, wtpb, tpb, 512, 512, 512, 512, 0,0,0, btp, nullptr,0,nullptr);
  mgemm_k<1,1><<<dim3(4,64,1),256,0,stream>>>(strb, wtcb, tcb, 512, 512, 512, 512, 0,0,0, btc, nullptr,0,nullptr);
  mgemm_k<0,1><<<dim3(4,64,1),256,0,stream>>>(tpb, wbilT, tpwb, 512, 512, 512, 512, 0,0,0, nullptr, nullptr,0,nullptr);
  mgemm_k<2,0><<<dim3(8,8,8),256,0,stream>>>(tpwb, tcb, Abuf, 512, 512, 512, 1024, 524288,524288,1048576, nullptr, nullptr,0,nullptr);
  castT_k<<<dim3(16,32,8), 256, 0, stream>>>(sem, semTb, 1024, 512, 524288, 524288);
  colsum_k<<<dim3(4,8),256,0,stream>>>(Abuf, cs);
  buildw_k<<<32768,256,0,stream>>>(Abuf, fi, cs, Wbuf, ColdA);
  // blocked in-place Gauss-Jordan inverse (fp32), ping-pong Cold panels
  for (int s = 0; s < 16; ++s) {
    int k0 = s * NB;
    float* Cin  = (s & 1) ? ColdB : ColdA;
    float* Cout = (s & 1) ? ColdA : ColdB;
    gj_dinv_k<<<8,256,0,stream>>>(Wbuf, Dinv, k0);
    gj_prep_k<<<dim3(64,8),256,0,stream>>>(Wbuf, Dinv, Rnew, k0);
    gupd_k<<<dim3(8,8,8),256,0,stream>>>(Cin, Rnew, Wbuf, Cout, k0);
  }
  ddiag_k<<<32,256,0,stream>>>(Wbuf, fi, d0, dg, dfp);
  dx_k<<<dim3(16,16,8),256,0,stream>>>(Abuf, Wbuf, dg, dfp, dxb, dxTb);
  semcopy_k<<<4096,256,0,stream>>>(sem, finpb);
  mgemm_k<4,1><<<dim3(4,8,8),256,0,stream>>>(dxTb, semTb, finpb + 512, 1024, 1024, 1024, 1536,
                                             1048576, 524288, 1572864, nullptr, d0, 1024, exparam);
  mgemm_k<0,1><<<dim3(4,8,8),256,0,stream>>>(dxb, semTb, finpb + 1024, 1024, 1024, 1024, 1536,
                                             1048576, 524288, 1572864, nullptr, nullptr,0,nullptr);
  mgemm_k<3,0><<<dim3(4,64,1),256,0,stream>>>(finpb, wfzb, outp, 1536, 1536, 1536, 512, 0,0,0, bfz, nullptr,0,nullptr);
}